// Round 3
// baseline (427.077 us; speedup 1.0000x reference)
//
#include <hip/hip_runtime.h>

#define HW     64
#define PLANE  4096   // 64*64
#define OW     62
#define NCH    512
#define NB     32
#define TOPK   256

typedef float floatx4 __attribute__((ext_vector_type(4)));
typedef const __attribute__((address_space(1))) unsigned int* gas_ptr;
typedef __attribute__((address_space(3))) unsigned int* las_ptr;

// ---------------------------------------------------------------------------
// Kernel 1: per-(b,c)-plane curvature score = sum |3x3 valid conv response|.
// One block per plane.
//
// Staging: async __builtin_amdgcn_global_load_lds (16 B/lane), LDS kept LINEAR
// (the instruction writes wave-uniform base + lane*16 — padding is illegal).
// Bank conflicts are instead solved by an XOR chunk swizzle applied on BOTH
// sides (rule: both-sides-or-neither):
//   LDS float4-chunk (row, c4) holds global chunk (row, c4 ^ (row & 15)).
// Read-side start bank = 4*(((4s+v)&7) ^ (row&7)); over a wave (r=0..15,
// s=0..3) each of the 8 start-bank groups gets exactly 8 lanes = 8 dwords
// per bank = the conflict-free minimum (same as the old LSTR=68 padding).
//
// Compute: thread (r = tid>>2, s = tid&3) evaluates output row r, cols
// s*16..s*16+15 (seg 3: 14 valid). Stencil in FP32 (jax's conv is fp32;
// ranking risk dominated by jax's own fp32 sum error), accumulate in DOUBLE.
// ---------------------------------------------------------------------------
__global__ __launch_bounds__(256) void score_kernel(const float* __restrict__ x,
                                                    double* __restrict__ p) {
    __shared__ float tile[PLANE];   // 16 KiB, linear, chunk-swizzled contents
    const int plane = blockIdx.x;
    const int tid = threadIdx.x;
    const float* src = x + (size_t)plane * PLANE;

    // ---- async stage: 4 calls; each wave writes 64 lanes x 16 B contiguous.
    // LDS chunk c = tid + 256*i  (row = c>>4, c4 = c&15); source chunk is the
    // row-local XOR-swizzled one. Wave-uniform LDS base = chunk (256*i + 64*w).
    #pragma unroll
    for (int i = 0; i < 4; ++i) {
        const int c   = tid + 256 * i;
        const int row = c >> 4;
        const int c4  = c & 15;
        const int gc  = (row << 4) + (c4  ^ (row & 15));
        __builtin_amdgcn_global_load_lds(
            (gas_ptr)(const void*)(src + gc * 4),
            (las_ptr)(void*)(tile + ((256 * i + (tid & ~63)) << 2)),
            16, 0, 0);
    }
    __syncthreads();   // drains vmcnt(0) -> staged data visible

    double acc = 0.0;
    if (tid < 248) {
        const int r  = tid >> 2;     // output row 0..61
        const int s  = tid & 3;      // column segment
        const int s4 = s * 4;        // first float4-chunk of this segment

        // ---- vector-load 3 input rows x 20 cols (5 swizzled chunks) ----
        float f0[20], f1[20], f2[20];
        const float* b0 = tile + r * HW;
        const float* b1 = b0 + HW;
        const float* b2 = b1 + HW;
        const int rx0 = r & 15, rx1 = (r + 1) & 15, rx2 = (r + 2) & 15;
        #pragma unroll
        for (int v = 0; v < 4; ++v) {
            *(float4*)(f0 + 4 * v) = *(const float4*)(b0 + (((s4 + v) ^ rx0) << 2));
            *(float4*)(f1 + 4 * v) = *(const float4*)(b1 + (((s4 + v) ^ rx1) << 2));
            *(float4*)(f2 + 4 * v) = *(const float4*)(b2 + (((s4 + v) ^ rx2) << 2));
        }
        if (s < 3) {
            *(float4*)(f0 + 16) = *(const float4*)(b0 + (((s4 + 4) ^ rx0) << 2));
            *(float4*)(f1 + 16) = *(const float4*)(b1 + (((s4 + 4) ^ rx1) << 2));
            *(float4*)(f2 + 16) = *(const float4*)(b2 + (((s4 + 4) ^ rx2) << 2));
        } else {
            #pragma unroll
            for (int j = 16; j < 20; ++j) { f0[j] = 0.f; f1[j] = 0.f; f2[j] = 0.f; }
        }

        const int nvalid = (s == 3) ? 14 : 16;   // seg 3 covers cols 48..61
        const float C5 = 0.3125f;    // 5/16, exact
        const float CM = -0.0625f;   // -1/16, exact

        #pragma unroll
        for (int u = 0; u < 16; ++u) {
            // vertical pair sums, grouped identically across u for CSE
            float a0 = f0[u]     + f2[u];
            float a1 = f0[u + 1] + f2[u + 1];
            float a2 = f0[u + 2] + f2[u + 2];
            float plus = a1 + f1[u] + f1[u + 2];
            float diag = a0 + a2;
            float resp = fmaf(C5, plus, fmaf(CM, diag, -f1[u + 1]));
            acc += (u < nvalid) ? (double)fabsf(resp) : 0.0;
        }
    }

    // ---- block reduce: 64-lane shuffle, then cross-wave LDS ----
    #pragma unroll
    for (int off = 32; off > 0; off >>= 1)
        acc += __shfl_down(acc, off, 64);

    __shared__ double wsum[4];
    const int wave = tid >> 6;
    if ((tid & 63) == 0) wsum[wave] = acc;
    __syncthreads();
    if (tid == 0)
        p[plane] = wsum[0] + wsum[1] + wsum[2] + wsum[3];
}

// ---------------------------------------------------------------------------
// Kernel 2: exact top-k by rank. One block per batch, 512 threads.
// rank[c] = #{j : p[j] > p[c]  or  (p[j]==p[c] and j<c)}  -- matches
// jax.lax.top_k ordering (descending, ties -> lower index first).
// ---------------------------------------------------------------------------
__global__ __launch_bounds__(512) void topk_kernel(const double* __restrict__ p,
                                                   int* __restrict__ idx) {
    __shared__ double sp[NCH];
    const int b = blockIdx.x;
    const int c = threadIdx.x;
    sp[c] = p[(size_t)b * NCH + c];
    __syncthreads();

    const double mine = sp[c];
    int rank = 0;
    for (int j = 0; j < NCH; ++j) {
        const double v = sp[j];
        rank += (v > mine) || (v == mine && j < c) ? 1 : 0;
    }
    if (rank < TOPK)
        idx[(size_t)b * TOPK + rank] = c;
}

// ---------------------------------------------------------------------------
// Kernel 3: gather selected channel planes. One block per (b, rank).
// REVERSED block order: score just streamed all 256 MiB of x through the
// 256 MiB L3, so the TAIL of x (high b) is most likely resident — gather
// batch 31 first. Output stores are non-temporal (never re-read) so they
// don't evict x from L3 while we still need it.
// ---------------------------------------------------------------------------
__global__ __launch_bounds__(256) void gather_kernel(const float* __restrict__ x,
                                                     const int* __restrict__ idx,
                                                     float* __restrict__ out) {
    const int bj = NB * TOPK - 1 - blockIdx.x;   // batch 31 first
    const int b = bj >> 8;                       // TOPK == 256
    const int ch = idx[bj];
    const floatx4* src = (const floatx4*)(x + ((size_t)b * NCH + ch) * PLANE);
    floatx4* dst = (floatx4*)(out + (size_t)bj * PLANE);
    const int tid = threadIdx.x;
    #pragma unroll
    for (int i = 0; i < 4; ++i) {
        floatx4 v = src[tid + 256 * i];
        __builtin_nontemporal_store(v, dst + tid + 256 * i);
    }
}

extern "C" void kernel_launch(void* const* d_in, const int* in_sizes, int n_in,
                              void* d_out, int out_size, void* d_ws, size_t ws_size,
                              hipStream_t stream) {
    const float* x = (const float*)d_in[0];
    float* out = (float*)d_out;

    // workspace layout: p (16384 doubles = 128 KB) | idx (8192 ints = 32 KB)
    double* p = (double*)d_ws;
    int* idx = (int*)((char*)d_ws + (size_t)NB * NCH * sizeof(double));

    score_kernel<<<NB * NCH, 256, 0, stream>>>(x, p);
    topk_kernel<<<NB, NCH, 0, stream>>>(p, idx);
    gather_kernel<<<NB * TOPK, 256, 0, stream>>>(x, idx, out);
}